// Round 4
// baseline (203.241 us; speedup 1.0000x reference)
//
#include <hip/hip_runtime.h>
#include <cstdint>
#include <cstddef>

typedef __attribute__((ext_vector_type(8))) short short8;
typedef __attribute__((ext_vector_type(4))) float floatx4;

#define NB 2
#define NPIX 2304
#define TBL 9025
#define TBLP 9032                      // padded to 8 for short8 copies
#define L2E 1.4426950408889634f
#define QSCALE 0.17677669529663689f    // 1/sqrt(32)
#define SPLIT 2
#define TILES_PER_SPLIT 18             // 36 key tiles / SPLIT

__device__ __forceinline__ float b2f(unsigned short u) {
  union { unsigned int i; float f; } v; v.i = ((unsigned int)u) << 16; return v.f;
}
__device__ __forceinline__ unsigned short f2b(float f) {
  union { float f; unsigned int i; } v; v.f = f;
  return (unsigned short)((v.i + 0x7fffu + ((v.i >> 16) & 1u)) >> 16);
}
// packed RNE f32->bf16 pair: low 16 = lo, high 16 = hi
__device__ __forceinline__ unsigned int cvtpk(float lo, float hi) {
  unsigned int r;
  asm("v_cvt_pk_bf16_f32 %0, %1, %2" : "=v"(r) : "v"(lo), "v"(hi));
  return r;
}

// ---------------------------------------------------------------------------
// Prep, blocks 0..767: fp32->bf16 weight conversion + per-head bias table
// gather (pre-scaled by log2(e)), tabt[h][e] stride TBLP.
// Blocks 768..1055: tiled transpose-square of x: xsq[b][n][c] = bf16(x[b][c][n]^2)
// ---------------------------------------------------------------------------
__global__ __launch_bounds__(256) void prep_k(
    const float* __restrict__ gamma, const float* __restrict__ wqkv,
    const float* __restrict__ wout, const float* __restrict__ table,
    const float* __restrict__ x,
    unsigned short* __restrict__ gb, unsigned short* __restrict__ qb,
    unsigned short* __restrict__ wb, unsigned short* __restrict__ tb,
    unsigned short* __restrict__ xsq)
{
  __shared__ unsigned short Ls[64][66];   // odd dword stride -> conflict-free col reads
  const int bx = blockIdx.x;
  const int tid = threadIdx.x;
  if (bx < 768) {
    int i = bx * 256 + tid;
    if (i < 65536)  gb[i] = f2b(gamma[i]);
    qb[i] = f2b(wqkv[i]);                 // grid covers exactly 196608
    if (i < 65536)  wb[i] = f2b(wout[i]);
    if (i < TBL * 8) {
      int e = i >> 3, h = i & 7;
      tb[(size_t)h * TBLP + e] = f2b(table[i] * L2E);
    }
    return;                               // barrier below is block-uniform
  }
  const int t = bx - 768;                 // 288 tiles: 2 b x 4 c-tiles x 36 n-tiles
  const int b = t / 144, r = t % 144;
  const int c0 = (r / 36) * 64, n0 = (r % 36) * 64;
  {
    const int ci = tid >> 2, ng = (tid & 3) * 16;
    const float* xr = &x[((size_t)(b * 256 + c0 + ci)) * NPIX + n0 + ng];
    unsigned int* dst = (unsigned int*)&Ls[ci][ng];
    #pragma unroll
    for (int j = 0; j < 4; ++j) {
      float4 v = *(const float4*)(xr + j * 4);
      dst[j * 2]     = cvtpk(v.x * v.x, v.y * v.y);
      dst[j * 2 + 1] = cvtpk(v.z * v.z, v.w * v.w);
    }
  }
  __syncthreads();
  {
    const int nr = tid >> 2, cc = (tid & 3) * 16;
    unsigned short* orow = &xsq[((size_t)(b * NPIX) + n0 + nr) * 256 + c0 + cc];
    unsigned short tmp[16];
    #pragma unroll
    for (int j = 0; j < 16; ++j) tmp[j] = Ls[cc + j][nr];
    *(short8*)&orow[0] = *(short8*)&tmp[0];
    *(short8*)&orow[8] = *(short8*)&tmp[8];
  }
}

// ---------------------------------------------------------------------------
// Latency-tolerant bf16 MFMA GEMM, K=256.  NO LDS, NO barriers.
// Each WAVE computes one 16x16 output tile: 8 K-steps x 1 MFMA, with all 16
// fragment loads (b128) independent and fully unrolled -> deep MLP per wave.
// Block = 4 waves = 32x32 tile.  Grids: mode0/2 1152 blocks, mode1 3456.
// MODE 0: norm = gamma @ x^2   -> xn = x*rsqrt(beta+norm), store xn^T [b][n][c]
// MODE 1: qkv  = w_qkv @ xn    -> q(*QSCALE*L2E)/k [b][h][n][32]; v TRANSPOSED [b][h][32][n]
// MODE 2: out  = w_out @ res^T + b_out -> FP32 [b][c][n]
// ---------------------------------------------------------------------------
template<int MODE>
__global__ __launch_bounds__(256) void gemm_k(
    const unsigned short* __restrict__ A,   // [M][256] bf16 weights
    const unsigned short* __restrict__ Bw,  // [b][2304][256] bf16
    const float* __restrict__ vec,          // beta (MODE0) / b_out (MODE2)
    const float* __restrict__ X,            // MODE0 only: fp32 x for epilogue
    unsigned short* __restrict__ o0,
    unsigned short* __restrict__ o1,
    unsigned short* __restrict__ o2,
    float* __restrict__ of)
{
  const int n0 = blockIdx.x * 32;
  const int m0 = blockIdx.y * 32;
  const int b  = blockIdx.z;
  const int tid = threadIdx.x;
  const int wave = tid >> 6, lane = tid & 63;
  const int wm = wave >> 1, wn = wave & 1;
  const int lm = lane & 15, quad = lane >> 4;

  const unsigned short* pa = &A[(size_t)(m0 + wm * 16 + lm) * 256 + quad * 8];
  const unsigned short* pb = &Bw[((size_t)b * NPIX + n0 + wn * 16 + lm) * 256 + quad * 8];

  floatx4 acc = {};
  #pragma unroll
  for (int k0 = 0; k0 < 256; k0 += 32) {
    short8 af = *(const short8*)(pa + k0);
    short8 bf = *(const short8*)(pb + k0);
    acc = __builtin_amdgcn_mfma_f32_16x16x32_bf16(af, bf, acc, 0, 0, 0);
  }

  // epilogue: D[row][col], row = quad*4+reg, col = lane&15
  const int rbase = m0 + wm * 16 + quad * 4;
  const int col = n0 + wn * 16 + lm;
  if (MODE == 0) {
    float xn[4];
    #pragma unroll
    for (int r = 0; r < 4; ++r) {
      int d = rbase + r;
      float xv = X[((size_t)(b * 256 + d)) * NPIX + col];
      xn[r] = xv * rsqrtf(vec[d] + acc[r]);
    }
    uint2 pk = { cvtpk(xn[0], xn[1]), cvtpk(xn[2], xn[3]) };
    *(uint2*)&o0[((size_t)(b * NPIX + col)) * 256 + rbase] = pk;
  } else if (MODE == 1) {
    const int part = rbase >> 8, h = (rbase >> 5) & 7, dd = rbase & 31;
    if (part == 2) {           // V transposed: [b][h][d][n]
      #pragma unroll
      for (int r = 0; r < 4; ++r)
        o2[(((size_t)(b * 8 + h)) * 32 + dd + r) * NPIX + col] = f2b(acc[r]);
    } else {
      unsigned short* dst = part == 0 ? o0 : o1;
      const float sc = (part == 0) ? (QSCALE * L2E) : 1.0f;
      uint2 pk = { cvtpk(acc[0] * sc, acc[1] * sc), cvtpk(acc[2] * sc, acc[3] * sc) };
      *(uint2*)&dst[(((size_t)(b * 8 + h)) * NPIX + col) * 32 + dd] = pk;
    }
  } else {
    #pragma unroll
    for (int r = 0; r < 4; ++r) {
      int c = rbase + r;
      of[((size_t)(b * 256 + c)) * NPIX + col] = acc[r] + vec[c];
    }
  }
}

// ---------------------------------------------------------------------------
// Split-K MFMA flash attention, software-pipelined.
// Grid (bh=16, qtile=36, split=2): flat blockid % 8 == bh % 8 -> each XCD owns
// 2 bh values (K/V/Q/bias working set ~1.2 MB, L2-hot).  4 waves, 16 q/wave.
// Per 64-key tile: V(t) + K(t+1) + bias(t+1) loads are ISSUED BEFORE the
// softmax / lgkmcnt clobber, so every global load has a full softmax phase
// (~600 cyc) to land -> no memory latency on the serial chain.  The only
// in-chain waits left: S-MFMA results and the P ds_write->ds_read round-trip.
// ---------------------------------------------------------------------------
__global__ __launch_bounds__(256) void attn_k(
    const unsigned short* __restrict__ qg, const unsigned short* __restrict__ kg,
    const unsigned short* __restrict__ vt, const unsigned short* __restrict__ tabt,
    float* __restrict__ po, float* __restrict__ pl)
{
  __shared__ __align__(16) unsigned short Pl[4][16][72]; // 9.2 KB, per-wave

  const int tid = threadIdx.x;
  const int w = tid >> 6, lane = tid & 63;
  const int lm = lane & 15, quad = lane >> 4;
  const int bh = blockIdx.x;
  const int q0 = blockIdx.y * 64;
  const int s  = blockIdx.z;
  const size_t base = (size_t)bh * NPIX * 32;   // q/k base; also vt base
  const unsigned short* __restrict__ tabg = tabt + (size_t)(bh & 7) * TBLP;

  // Q fragment: B-operand for S^T (n=lm=q, k=quad*8+j=d); pre-scaled QSCALE*L2E
  const int q = q0 + w * 16 + lm;
  const short8 qfrag = *(const short8*)&qg[base + (size_t)q * 32 + quad * 8];

  // bias row base for this lane's query
  const int hi = (q * 43691) >> 21;                  // q / 48
  const int rb = (hi + 47) * 95 + (q - hi * 48) + 47;

  float lsum = 0.f;
  floatx4 o[2] = {};

  // ---- prologue: prefetch K + bias for tile 0 of this split ----
  short8 kf[4];
  unsigned short br[16];
  {
    const int j0 = s * TILES_PER_SPLIT * 64;
    #pragma unroll
    for (int kt = 0; kt < 4; ++kt)
      kf[kt] = *(const short8*)&kg[base + (size_t)(j0 + kt * 16 + lm) * 32 + quad * 8];
    #pragma unroll
    for (int kt = 0; kt < 4; ++kt) {
      const int kk = j0 + kt * 16 + quad * 4;
      const int hj = (kk * 43691) >> 21;             // = key/48 for all 4 keys
      const int bb = rb - kk - hj * 47;
      #pragma unroll
      for (int r = 0; r < 4; ++r) br[kt * 4 + r] = tabg[bb - r];
    }
  }

  for (int tt = 0; tt < TILES_PER_SPLIT; ++tt) {
    const int j0 = (s * TILES_PER_SPLIT + tt) * 64;
    const int tn = (tt + 1 < TILES_PER_SPLIT) ? tt + 1 : tt;
    const int j0n = (s * TILES_PER_SPLIT + tn) * 64;

    // issue V(t) loads now -- consumed only after softmax
    short8 vf[2][2];
    #pragma unroll
    for (int c = 0; c < 2; ++c)
      #pragma unroll
      for (int dt = 0; dt < 2; ++dt)
        vf[c][dt] = *(const short8*)&vt[base + (size_t)(dt * 16 + lm) * NPIX + j0 + c * 32 + quad * 8];

    // S^T[key][q] from prefetched K
    floatx4 s4[4];
    #pragma unroll
    for (int kt = 0; kt < 4; ++kt) {
      floatx4 z = {};
      s4[kt] = __builtin_amdgcn_mfma_f32_16x16x32_bf16(kf[kt], qfrag, z, 0, 0, 0);
    }

    // prefetch K(t+1) + bias(t+1) -- in flight across the softmax phase
    short8 kfn[4];
    unsigned short brn[16];
    #pragma unroll
    for (int kt = 0; kt < 4; ++kt)
      kfn[kt] = *(const short8*)&kg[base + (size_t)(j0n + kt * 16 + lm) * 32 + quad * 8];
    #pragma unroll
    for (int kt = 0; kt < 4; ++kt) {
      const int kk = j0n + kt * 16 + quad * 4;
      const int hj = (kk * 43691) >> 21;
      const int bb = rb - kk - hj * 47;
      #pragma unroll
      for (int r = 0; r < 4; ++r) brn[kt * 4 + r] = tabg[bb - r];
    }

    // softmax with current-tile bias (registers), pack P, ds_write
    #pragma unroll
    for (int kt = 0; kt < 4; ++kt) {
      float pv[4];
      #pragma unroll
      for (int r = 0; r < 4; ++r) {
        float p = exp2f(s4[kt][r] + b2f(br[kt * 4 + r]));
        lsum += p;
        pv[r] = p;
      }
      uint2 pk = { cvtpk(pv[0], pv[1]), cvtpk(pv[2], pv[3]) };
      *(uint2*)&Pl[w][lm][kt * 16 + quad * 4] = pk;  // P[q][key] layout
    }
    __asm__ volatile("s_waitcnt lgkmcnt(0)" ::: "memory"); // wave-local DS order

    // O^T[d][q] += V^T[d][key] * P^T[key][q]  (vf already resident)
    #pragma unroll
    for (int c = 0; c < 2; ++c) {
      short8 pf = *(const short8*)&Pl[w][lm][c * 32 + quad * 8];
      #pragma unroll
      for (int dt = 0; dt < 2; ++dt)
        o[dt] = __builtin_amdgcn_mfma_f32_16x16x32_bf16(vf[c][dt], pf, o[dt], 0, 0, 0);
    }

    // rotate prefetch registers
    #pragma unroll
    for (int kt = 0; kt < 4; ++kt) kf[kt] = kfn[kt];
    #pragma unroll
    for (int i = 0; i < 16; ++i) br[i] = brn[i];
  }

  // reduce l across the 4 quads holding the same query
  lsum += __shfl_xor(lsum, 16, 64);
  lsum += __shfl_xor(lsum, 32, 64);

  // write f32 partials: lane holds d = dt*16 + quad*4 + r at its query q
  const size_t pbase = ((size_t)(s * 16 + bh) * NPIX + q) * 32;
  *(floatx4*)&po[pbase + quad * 4]      = o[0];
  *(floatx4*)&po[pbase + 16 + quad * 4] = o[1];
  if (quad == 0) pl[(size_t)(s * 16 + bh) * NPIX + q] = lsum;
}

// ---------------------------------------------------------------------------
// Combine SPLIT partial (O, l) -> bf16 attention output [bh][q][32]
// ---------------------------------------------------------------------------
__global__ __launch_bounds__(256) void reduce_k(
    const float* __restrict__ po, const float* __restrict__ pl,
    unsigned short* __restrict__ ob)
{
  const int tid = threadIdx.x;
  const int bh = blockIdx.y;
  const int q = blockIdx.x * 32 + (tid >> 3);
  const int d4 = (tid & 7) * 4;
  const size_t st = (size_t)16 * NPIX * 32;
  const size_t i0 = ((size_t)bh * NPIX + q) * 32 + d4;
  floatx4 a = *(const floatx4*)&po[i0];
  floatx4 b = *(const floatx4*)&po[i0 + st];
  a += b;
  const size_t li = (size_t)bh * NPIX + q;
  const float inv = 1.f / (pl[li] + pl[li + (size_t)16 * NPIX]);
  uint2 pk = { cvtpk(a[0] * inv, a[1] * inv), cvtpk(a[2] * inv, a[3] * inv) };
  *(uint2*)&ob[((size_t)bh * NPIX + q) * 32 + d4] = pk;
}

// ---------------------------------------------------------------------------
extern "C" void kernel_launch(void* const* d_in, const int* in_sizes, int n_in,
                              void* d_out, int out_size, void* d_ws, size_t ws_size,
                              hipStream_t stream) {
  const float* x     = (const float*)d_in[0];
  const float* beta  = (const float*)d_in[1];
  const float* gamma = (const float*)d_in[2];
  const float* wqkv  = (const float*)d_in[3];
  const float* wout  = (const float*)d_in[4];
  const float* bout  = (const float*)d_in[5];
  const float* table = (const float*)d_in[6];
  float* out = (float*)d_out;   // reference output dtype is float32

  unsigned short* ws = (unsigned short*)d_ws;
  const size_t NE = (size_t)NB * NPIX * 256;   // 1,179,648 elems per tensor
  unsigned short* xn_t  = ws;                  // [b][n][256] bf16
  unsigned short* qbuf  = ws + NE;             // [b][h][n][32] bf16, *QSCALE*L2E
  unsigned short* kbuf  = ws + 2 * NE;         // [b][h][n][32]
  unsigned short* vtbuf = ws + 3 * NE;         // [b][h][32][n]  (transposed)
  unsigned short* obuf  = ws + 4 * NE;         // [b][h][n][32] == res[b][n2][e]
  // bf16 weights: gamma/wqkv alias obuf (dead before reduce writes it)
  unsigned short* gam_b = obuf;                // 65536
  unsigned short* qkv_b = obuf + 65536;        // 196608 (fits in NE)
  unsigned short* out_b = ws + 5 * NE;         // 65536 (live through gemm2)
  unsigned short* tab_t = ws + 5 * NE + 65536; // 8*TBLP (live through attn)
  // split-K partials after tab_t (16B-aligned)
  float* po = (float*)(ws + 5 * NE + 65536 + 8 * TBLP);  // [2][16][2304][32] f32
  float* pl = po + (size_t)SPLIT * 16 * NPIX * 32;       // [2][16][2304] f32
  // xsq aliases qbuf: written by prep, consumed by gemm0, overwritten by gemm1
  unsigned short* xsq   = qbuf;                // [b][n][256] bf16 = x^2 transposed

  prep_k<<<1056, 256, 0, stream>>>(gamma, wqkv, wout, table, x,
                                   gam_b, qkv_b, out_b, tab_t, xsq);
  gemm_k<0><<<dim3(72, 8, 2), 256, 0, stream>>>(gam_b, xsq, beta, x,
                                                xn_t, nullptr, nullptr, nullptr);
  gemm_k<1><<<dim3(72, 24, 2), 256, 0, stream>>>(qkv_b, xn_t, nullptr, nullptr,
                                                 qbuf, kbuf, vtbuf, nullptr);
  attn_k<<<dim3(16, 36, SPLIT), 256, 0, stream>>>(qbuf, kbuf, vtbuf, tab_t, po, pl);
  reduce_k<<<dim3(72, 16), 256, 0, stream>>>(po, pl, obuf);
  gemm_k<2><<<dim3(72, 8, 2), 256, 0, stream>>>(out_b, obuf, bout, nullptr,
                                                nullptr, nullptr, nullptr, out);
}

// Round 8
// 199.510 us; speedup vs baseline: 1.0187x; 1.0187x over previous
//
#include <hip/hip_runtime.h>
#include <cstdint>
#include <cstddef>

typedef __attribute__((ext_vector_type(8))) short short8;
typedef __attribute__((ext_vector_type(4))) float floatx4;

#define NB 2
#define NPIX 2304
#define TBL 9025
#define TBLP 9032                      // padded to 8 for short8 copies
#define L2E 1.4426950408889634f
#define QSCALE 0.17677669529663689f    // 1/sqrt(32)
#define NTILES 36

__device__ __forceinline__ float b2f(unsigned short u) {
  union { unsigned int i; float f; } v; v.i = ((unsigned int)u) << 16; return v.f;
}
__device__ __forceinline__ unsigned short f2b(float f) {
  union { float f; unsigned int i; } v; v.f = f;
  return (unsigned short)((v.i + 0x7fffu + ((v.i >> 16) & 1u)) >> 16);
}
// packed RNE f32->bf16 pair: low 16 = lo, high 16 = hi
__device__ __forceinline__ unsigned int cvtpk(float lo, float hi) {
  unsigned int r;
  asm("v_cvt_pk_bf16_f32 %0, %1, %2" : "=v"(r) : "v"(lo), "v"(hi));
  return r;
}

// ---------------------------------------------------------------------------
// Prep, blocks 0..767: fp32->bf16 weight conversion + per-head bias table
// gather (pre-scaled by log2(e)), tabt[h][e] stride TBLP.
// Blocks 768..1055: tiled transpose-square of x: xsq[b][n][c] = bf16(x[b][c][n]^2)
// ---------------------------------------------------------------------------
__global__ __launch_bounds__(256) void prep_k(
    const float* __restrict__ gamma, const float* __restrict__ wqkv,
    const float* __restrict__ wout, const float* __restrict__ table,
    const float* __restrict__ x,
    unsigned short* __restrict__ gb, unsigned short* __restrict__ qb,
    unsigned short* __restrict__ wb, unsigned short* __restrict__ tb,
    unsigned short* __restrict__ xsq)
{
  __shared__ unsigned short Ls[64][66];   // odd dword stride -> conflict-free col reads
  const int bx = blockIdx.x;
  const int tid = threadIdx.x;
  if (bx < 768) {
    int i = bx * 256 + tid;
    if (i < 65536)  gb[i] = f2b(gamma[i]);
    qb[i] = f2b(wqkv[i]);                 // grid covers exactly 196608
    if (i < 65536)  wb[i] = f2b(wout[i]);
    if (i < TBL * 8) {
      int e = i >> 3, h = i & 7;
      tb[(size_t)h * TBLP + e] = f2b(table[i] * L2E);
    }
    return;                               // barrier below is block-uniform
  }
  const int t = bx - 768;                 // 288 tiles: 2 b x 4 c-tiles x 36 n-tiles
  const int b = t / 144, r = t % 144;
  const int c0 = (r / 36) * 64, n0 = (r % 36) * 64;
  {
    const int ci = tid >> 2, ng = (tid & 3) * 16;
    const float* xr = &x[((size_t)(b * 256 + c0 + ci)) * NPIX + n0 + ng];
    unsigned int* dst = (unsigned int*)&Ls[ci][ng];
    #pragma unroll
    for (int j = 0; j < 4; ++j) {
      float4 v = *(const float4*)(xr + j * 4);
      dst[j * 2]     = cvtpk(v.x * v.x, v.y * v.y);
      dst[j * 2 + 1] = cvtpk(v.z * v.z, v.w * v.w);
    }
  }
  __syncthreads();
  {
    const int nr = tid >> 2, cc = (tid & 3) * 16;
    unsigned short* orow = &xsq[((size_t)(b * NPIX) + n0 + nr) * 256 + c0 + cc];
    unsigned short tmp[16];
    #pragma unroll
    for (int j = 0; j < 16; ++j) tmp[j] = Ls[cc + j][nr];
    *(short8*)&orow[0] = *(short8*)&tmp[0];
    *(short8*)&orow[8] = *(short8*)&tmp[8];
  }
}

// ---------------------------------------------------------------------------
// Barrier-free 64x64-tile bf16 MFMA GEMM, K=256.  NO LDS, NO __syncthreads.
// (R3-measured configuration: best of the three GEMM structures tried.)
// MODE 0: norm = gamma @ x^2   -> xn = x*rsqrt(beta+norm), store xn^T [b][n][c]
// MODE 1: qkv  = w_qkv @ xn    -> q(*QSCALE*L2E)/k [b][h][n][32]; v TRANSPOSED [b][h][32][n]
// MODE 2: out  = w_out @ res^T + b_out -> FP32 [b][c][n]
// ---------------------------------------------------------------------------
template<int MODE>
__global__ __launch_bounds__(256) void gemm_k(
    const unsigned short* __restrict__ A,   // [M][256] bf16 weights
    const unsigned short* __restrict__ Bw,  // [b][2304][256] bf16
    const float* __restrict__ vec,          // beta (MODE0) / b_out (MODE2)
    const float* __restrict__ X,            // MODE0 only: fp32 x for epilogue
    unsigned short* __restrict__ o0,
    unsigned short* __restrict__ o1,
    unsigned short* __restrict__ o2,
    float* __restrict__ of)
{
  const int n0 = blockIdx.x * 64;
  const int m0 = blockIdx.y * 64;
  const int b  = blockIdx.z;
  const int tid = threadIdx.x;
  const int wave = tid >> 6, lane = tid & 63;
  const int wm = wave >> 1, wn = wave & 1;
  const int lm = lane & 15, quad = lane >> 4;

  const unsigned short* pa = &A[(size_t)(m0 + wm * 32 + lm) * 256 + quad * 8];
  const unsigned short* pb = &Bw[((size_t)b * NPIX + n0 + wn * 32 + lm) * 256 + quad * 8];

  floatx4 acc[2][2] = {};
  #pragma unroll
  for (int k0 = 0; k0 < 256; k0 += 32) {
    short8 af0 = *(const short8*)(pa + k0);
    short8 af1 = *(const short8*)(pa + 16 * 256 + k0);
    short8 bf0 = *(const short8*)(pb + k0);
    short8 bf1 = *(const short8*)(pb + 16 * 256 + k0);
    acc[0][0] = __builtin_amdgcn_mfma_f32_16x16x32_bf16(af0, bf0, acc[0][0], 0, 0, 0);
    acc[0][1] = __builtin_amdgcn_mfma_f32_16x16x32_bf16(af0, bf1, acc[0][1], 0, 0, 0);
    acc[1][0] = __builtin_amdgcn_mfma_f32_16x16x32_bf16(af1, bf0, acc[1][0], 0, 0, 0);
    acc[1][1] = __builtin_amdgcn_mfma_f32_16x16x32_bf16(af1, bf1, acc[1][1], 0, 0, 0);
  }

  // epilogue: D[row][col], row = quad*4+reg (+tile), col = lane&15 (+tile)
  #pragma unroll
  for (int tm = 0; tm < 2; ++tm) {
    const int rbase = m0 + wm * 32 + tm * 16 + quad * 4;
    #pragma unroll
    for (int tn = 0; tn < 2; ++tn) {
      const int col = n0 + wn * 32 + tn * 16 + lm;
      floatx4 a4 = acc[tm][tn];
      if (MODE == 0) {
        float xn[4];
        #pragma unroll
        for (int r = 0; r < 4; ++r) {
          int d = rbase + r;
          float xv = X[((size_t)(b * 256 + d)) * NPIX + col];
          xn[r] = xv * rsqrtf(vec[d] + a4[r]);
        }
        uint2 pk = { cvtpk(xn[0], xn[1]), cvtpk(xn[2], xn[3]) };
        *(uint2*)&o0[((size_t)(b * NPIX + col)) * 256 + rbase] = pk;
      } else if (MODE == 1) {
        const int part = rbase >> 8, h = (rbase >> 5) & 7, dd = rbase & 31;
        if (part == 2) {           // V transposed: [b][h][d][n]
          #pragma unroll
          for (int r = 0; r < 4; ++r)
            o2[(((size_t)(b * 8 + h)) * 32 + dd + r) * NPIX + col] = f2b(a4[r]);
        } else {
          unsigned short* dst = part == 0 ? o0 : o1;
          const float sc = (part == 0) ? (QSCALE * L2E) : 1.0f;
          uint2 pk = { cvtpk(a4[0] * sc, a4[1] * sc), cvtpk(a4[2] * sc, a4[3] * sc) };
          *(uint2*)&dst[(((size_t)(b * 8 + h)) * NPIX + col) * 32 + dd] = pk;
        }
      } else {
        #pragma unroll
        for (int r = 0; r < 4; ++r) {
          int c = rbase + r;
          of[((size_t)(b * 256 + c)) * NPIX + col] = a4[r] + vec[c];
        }
      }
    }
  }
}

// ---------------------------------------------------------------------------
// Attention: R4-MEASURED structure (passed, 83us) with the single validated
// delta SPLIT 2->1 (direct per-lane normalize + bf16 store, the R0-measured
// combination).  Grid (bh=16, qtile=36), 4 waves, 16 q/wave.
// Per 64-key tile: V(t), K(t+1), bias(t+1) issued before the softmax /
// lgkmcnt clobber; VALU lsum + shfl_xor quad reduce; library exp2f;
// explicit prefetch-register rotation.  (R7's ping-pong macro / builtin
// exp2 / ones-MFMA-per-lane combination failed correctness and is parked.)
// ---------------------------------------------------------------------------
__global__ __launch_bounds__(256) void attn_k(
    const unsigned short* __restrict__ qg, const unsigned short* __restrict__ kg,
    const unsigned short* __restrict__ vt, const unsigned short* __restrict__ tabt,
    unsigned short* __restrict__ ob)
{
  __shared__ __align__(16) unsigned short Pl[4][16][72]; // 9.2 KB, per-wave

  const int tid = threadIdx.x;
  const int w = tid >> 6, lane = tid & 63;
  const int lm = lane & 15, quad = lane >> 4;
  const int bh = blockIdx.x;
  const int q0 = blockIdx.y * 64;
  const size_t base = (size_t)bh * NPIX * 32;   // q/k base; also vt base
  const unsigned short* __restrict__ tabg = tabt + (size_t)(bh & 7) * TBLP;

  // Q fragment: B-operand for S^T (n=lm=q, k=quad*8+j=d); pre-scaled QSCALE*L2E
  const int q = q0 + w * 16 + lm;
  const short8 qfrag = *(const short8*)&qg[base + (size_t)q * 32 + quad * 8];

  // bias row base for this lane's query
  const int hi = (q * 43691) >> 21;                  // q / 48
  const int rb = (hi + 47) * 95 + (q - hi * 48) + 47;

  float lsum = 0.f;
  floatx4 o[2] = {};

  // ---- prologue: prefetch K + bias for tile 0 ----
  short8 kf[4];
  unsigned short br[16];
  {
    #pragma unroll
    for (int kt = 0; kt < 4; ++kt)
      kf[kt] = *(const short8*)&kg[base + (size_t)(kt * 16 + lm) * 32 + quad * 8];
    #pragma unroll
    for (int kt = 0; kt < 4; ++kt) {
      const int kk = kt * 16 + quad * 4;
      const int hj = (kk * 43691) >> 21;             // = key/48 for all 4 keys
      const int bb = rb - kk - hj * 47;
      #pragma unroll
      for (int r = 0; r < 4; ++r) br[kt * 4 + r] = tabg[bb - r];
    }
  }

  for (int tt = 0; tt < NTILES; ++tt) {
    const int j0 = tt * 64;
    const int tn = (tt + 1 < NTILES) ? tt + 1 : tt;
    const int j0n = tn * 64;

    // issue V(t) loads now -- consumed only after softmax
    short8 vf[2][2];
    #pragma unroll
    for (int c = 0; c < 2; ++c)
      #pragma unroll
      for (int dt = 0; dt < 2; ++dt)
        vf[c][dt] = *(const short8*)&vt[base + (size_t)(dt * 16 + lm) * NPIX + j0 + c * 32 + quad * 8];

    // S^T[key][q] from prefetched K
    floatx4 s4[4];
    #pragma unroll
    for (int kt = 0; kt < 4; ++kt) {
      floatx4 z = {};
      s4[kt] = __builtin_amdgcn_mfma_f32_16x16x32_bf16(kf[kt], qfrag, z, 0, 0, 0);
    }

    // prefetch K(t+1) + bias(t+1) -- in flight across the softmax phase
    short8 kfn[4];
    unsigned short brn[16];
    #pragma unroll
    for (int kt = 0; kt < 4; ++kt)
      kfn[kt] = *(const short8*)&kg[base + (size_t)(j0n + kt * 16 + lm) * 32 + quad * 8];
    #pragma unroll
    for (int kt = 0; kt < 4; ++kt) {
      const int kk = j0n + kt * 16 + quad * 4;
      const int hj = (kk * 43691) >> 21;
      const int bb = rb - kk - hj * 47;
      #pragma unroll
      for (int r = 0; r < 4; ++r) brn[kt * 4 + r] = tabg[bb - r];
    }

    // softmax with current-tile bias (registers), pack P, ds_write
    #pragma unroll
    for (int kt = 0; kt < 4; ++kt) {
      float pv[4];
      #pragma unroll
      for (int r = 0; r < 4; ++r) {
        float p = exp2f(s4[kt][r] + b2f(br[kt * 4 + r]));
        lsum += p;
        pv[r] = p;
      }
      uint2 pk = { cvtpk(pv[0], pv[1]), cvtpk(pv[2], pv[3]) };
      *(uint2*)&Pl[w][lm][kt * 16 + quad * 4] = pk;  // P[q][key] layout
    }
    __asm__ volatile("s_waitcnt lgkmcnt(0)" ::: "memory"); // wave-local DS order

    // O^T[d][q] += V^T[d][key] * P^T[key][q]  (vf already resident)
    #pragma unroll
    for (int c = 0; c < 2; ++c) {
      short8 pf = *(const short8*)&Pl[w][lm][c * 32 + quad * 8];
      #pragma unroll
      for (int dt = 0; dt < 2; ++dt)
        o[dt] = __builtin_amdgcn_mfma_f32_16x16x32_bf16(vf[c][dt], pf, o[dt], 0, 0, 0);
    }

    // rotate prefetch registers
    #pragma unroll
    for (int kt = 0; kt < 4; ++kt) kf[kt] = kfn[kt];
    #pragma unroll
    for (int i = 0; i < 16; ++i) br[i] = brn[i];
  }

  // reduce l across the 4 quads holding the same query
  lsum += __shfl_xor(lsum, 16, 64);
  lsum += __shfl_xor(lsum, 32, 64);
  const float inv = 1.f / lsum;

  // store O[q][d] bf16: lane holds d = dt*16 + quad*4 + r at its query q
  #pragma unroll
  for (int dt = 0; dt < 2; ++dt) {
    uint2 pk = { cvtpk(o[dt][0] * inv, o[dt][1] * inv),
                 cvtpk(o[dt][2] * inv, o[dt][3] * inv) };
    *(uint2*)&ob[base + (size_t)q * 32 + dt * 16 + quad * 4] = pk;
  }
}

// ---------------------------------------------------------------------------
extern "C" void kernel_launch(void* const* d_in, const int* in_sizes, int n_in,
                              void* d_out, int out_size, void* d_ws, size_t ws_size,
                              hipStream_t stream) {
  const float* x     = (const float*)d_in[0];
  const float* beta  = (const float*)d_in[1];
  const float* gamma = (const float*)d_in[2];
  const float* wqkv  = (const float*)d_in[3];
  const float* wout  = (const float*)d_in[4];
  const float* bout  = (const float*)d_in[5];
  const float* table = (const float*)d_in[6];
  float* out = (float*)d_out;   // reference output dtype is float32

  unsigned short* ws = (unsigned short*)d_ws;
  const size_t NE = (size_t)NB * NPIX * 256;   // 1,179,648 elems per tensor
  unsigned short* xn_t  = ws;                  // [b][n][256] bf16
  unsigned short* qbuf  = ws + NE;             // [b][h][n][32] bf16, *QSCALE*L2E
  unsigned short* kbuf  = ws + 2 * NE;         // [b][h][n][32]
  unsigned short* vtbuf = ws + 3 * NE;         // [b][h][32][n]  (transposed)
  unsigned short* obuf  = ws + 4 * NE;         // [b][h][n][32] == res[b][n2][e]
  // bf16 weights: gamma/wqkv alias obuf (dead before attn writes it)
  unsigned short* gam_b = obuf;                // 65536
  unsigned short* qkv_b = obuf + 65536;        // 196608 (fits in NE)
  unsigned short* out_b = ws + 5 * NE;         // 65536 (live through gemm2)
  unsigned short* tab_t = ws + 5 * NE + 65536; // 8*TBLP (live through attn)
  // xsq aliases qbuf: written by prep, consumed by gemm0, overwritten by gemm1
  unsigned short* xsq   = qbuf;                // [b][n][256] bf16 = x^2 transposed

  prep_k<<<1056, 256, 0, stream>>>(gamma, wqkv, wout, table, x,
                                   gam_b, qkv_b, out_b, tab_t, xsq);
  gemm_k<0><<<dim3(36, 4, 2), 256, 0, stream>>>(gam_b, xsq, beta, x,
                                                xn_t, nullptr, nullptr, nullptr);
  gemm_k<1><<<dim3(36, 12, 2), 256, 0, stream>>>(qkv_b, xn_t, nullptr, nullptr,
                                                 qbuf, kbuf, vtbuf, nullptr);
  attn_k<<<dim3(16, 36), 256, 0, stream>>>(qbuf, kbuf, vtbuf, tab_t, obuf);
  gemm_k<2><<<dim3(36, 4, 2), 256, 0, stream>>>(out_b, obuf, bout, nullptr,
                                                nullptr, nullptr, nullptr, out);
}

// Round 10
// 167.061 us; speedup vs baseline: 1.2166x; 1.1942x over previous
//
#include <hip/hip_runtime.h>
#include <cstdint>
#include <cstddef>

typedef __attribute__((ext_vector_type(8))) short short8;
typedef __attribute__((ext_vector_type(4))) float floatx4;

#define NB 2
#define NPIX 2304
#define TBL 9025
#define TBLP 9032                      // padded to 8 for short8 copies
#define L2E 1.4426950408889634f
#define QSCALE 0.17677669529663689f    // 1/sqrt(32)
#define NTILES 36

__device__ __forceinline__ float b2f(unsigned short u) {
  union { unsigned int i; float f; } v; v.i = ((unsigned int)u) << 16; return v.f;
}
__device__ __forceinline__ unsigned short f2b(float f) {
  union { float f; unsigned int i; } v; v.f = f;
  return (unsigned short)((v.i + 0x7fffu + ((v.i >> 16) & 1u)) >> 16);
}
// packed RNE f32->bf16 pair: low 16 = lo, high 16 = hi
__device__ __forceinline__ unsigned int cvtpk(float lo, float hi) {
  unsigned int r;
  asm("v_cvt_pk_bf16_f32 %0, %1, %2" : "=v"(r) : "v"(lo), "v"(hi));
  return r;
}

// ---------------------------------------------------------------------------
// Prep, blocks 0..767: fp32->bf16 weight conversion + per-head bias table
// gather (pre-scaled by log2(e)), tabt[h][e] stride TBLP.
// Blocks 768..1055: tiled transpose-square of x: xsq[b][n][c] = bf16(x[b][c][n]^2)
// ---------------------------------------------------------------------------
__global__ __launch_bounds__(256) void prep_k(
    const float* __restrict__ gamma, const float* __restrict__ wqkv,
    const float* __restrict__ wout, const float* __restrict__ table,
    const float* __restrict__ x,
    unsigned short* __restrict__ gb, unsigned short* __restrict__ qb,
    unsigned short* __restrict__ wb, unsigned short* __restrict__ tb,
    unsigned short* __restrict__ xsq)
{
  __shared__ unsigned short Ls[64][66];   // odd dword stride -> conflict-free col reads
  const int bx = blockIdx.x;
  const int tid = threadIdx.x;
  if (bx < 768) {
    int i = bx * 256 + tid;
    if (i < 65536)  gb[i] = f2b(gamma[i]);
    qb[i] = f2b(wqkv[i]);                 // grid covers exactly 196608
    if (i < 65536)  wb[i] = f2b(wout[i]);
    if (i < TBL * 8) {
      int e = i >> 3, h = i & 7;
      tb[(size_t)h * TBLP + e] = f2b(table[i] * L2E);
    }
    return;                               // barrier below is block-uniform
  }
  const int t = bx - 768;                 // 288 tiles: 2 b x 4 c-tiles x 36 n-tiles
  const int b = t / 144, r = t % 144;
  const int c0 = (r / 36) * 64, n0 = (r % 36) * 64;
  {
    const int ci = tid >> 2, ng = (tid & 3) * 16;
    const float* xr = &x[((size_t)(b * 256 + c0 + ci)) * NPIX + n0 + ng];
    unsigned int* dst = (unsigned int*)&Ls[ci][ng];
    #pragma unroll
    for (int j = 0; j < 4; ++j) {
      float4 v = *(const float4*)(xr + j * 4);
      dst[j * 2]     = cvtpk(v.x * v.x, v.y * v.y);
      dst[j * 2 + 1] = cvtpk(v.z * v.z, v.w * v.w);
    }
  }
  __syncthreads();
  {
    const int nr = tid >> 2, cc = (tid & 3) * 16;
    unsigned short* orow = &xsq[((size_t)(b * NPIX) + n0 + nr) * 256 + c0 + cc];
    unsigned short tmp[16];
    #pragma unroll
    for (int j = 0; j < 16; ++j) tmp[j] = Ls[cc + j][nr];
    *(short8*)&orow[0] = *(short8*)&tmp[0];
    *(short8*)&orow[8] = *(short8*)&tmp[8];
  }
}

// ---------------------------------------------------------------------------
// Barrier-free 64x64-tile bf16 MFMA GEMM, K=256.  NO LDS, NO __syncthreads.
// (R3-measured configuration: best of the three GEMM structures tried.)
// MODE 0: norm = gamma @ x^2   -> xn = x*rsqrt(beta+norm), store xn^T [b][n][c]
// MODE 1: qkv  = w_qkv @ xn    -> q(*QSCALE*L2E)/k [b][h][n][32]; v TRANSPOSED [b][h][32][n]
// MODE 2: out  = w_out @ res^T + b_out -> FP32 [b][c][n]
// ---------------------------------------------------------------------------
template<int MODE>
__global__ __launch_bounds__(256) void gemm_k(
    const unsigned short* __restrict__ A,   // [M][256] bf16 weights
    const unsigned short* __restrict__ Bw,  // [b][2304][256] bf16
    const float* __restrict__ vec,          // beta (MODE0) / b_out (MODE2)
    const float* __restrict__ X,            // MODE0 only: fp32 x for epilogue
    unsigned short* __restrict__ o0,
    unsigned short* __restrict__ o1,
    unsigned short* __restrict__ o2,
    float* __restrict__ of)
{
  const int n0 = blockIdx.x * 64;
  const int m0 = blockIdx.y * 64;
  const int b  = blockIdx.z;
  const int tid = threadIdx.x;
  const int wave = tid >> 6, lane = tid & 63;
  const int wm = wave >> 1, wn = wave & 1;
  const int lm = lane & 15, quad = lane >> 4;

  const unsigned short* pa = &A[(size_t)(m0 + wm * 32 + lm) * 256 + quad * 8];
  const unsigned short* pb = &Bw[((size_t)b * NPIX + n0 + wn * 32 + lm) * 256 + quad * 8];

  floatx4 acc[2][2] = {};
  #pragma unroll
  for (int k0 = 0; k0 < 256; k0 += 32) {
    short8 af0 = *(const short8*)(pa + k0);
    short8 af1 = *(const short8*)(pa + 16 * 256 + k0);
    short8 bf0 = *(const short8*)(pb + k0);
    short8 bf1 = *(const short8*)(pb + 16 * 256 + k0);
    acc[0][0] = __builtin_amdgcn_mfma_f32_16x16x32_bf16(af0, bf0, acc[0][0], 0, 0, 0);
    acc[0][1] = __builtin_amdgcn_mfma_f32_16x16x32_bf16(af0, bf1, acc[0][1], 0, 0, 0);
    acc[1][0] = __builtin_amdgcn_mfma_f32_16x16x32_bf16(af1, bf0, acc[1][0], 0, 0, 0);
    acc[1][1] = __builtin_amdgcn_mfma_f32_16x16x32_bf16(af1, bf1, acc[1][1], 0, 0, 0);
  }

  // epilogue: D[row][col], row = quad*4+reg (+tile), col = lane&15 (+tile)
  #pragma unroll
  for (int tm = 0; tm < 2; ++tm) {
    const int rbase = m0 + wm * 32 + tm * 16 + quad * 4;
    #pragma unroll
    for (int tn = 0; tn < 2; ++tn) {
      const int col = n0 + wn * 32 + tn * 16 + lm;
      floatx4 a4 = acc[tm][tn];
      if (MODE == 0) {
        float xn[4];
        #pragma unroll
        for (int r = 0; r < 4; ++r) {
          int d = rbase + r;
          float xv = X[((size_t)(b * 256 + d)) * NPIX + col];
          xn[r] = xv * rsqrtf(vec[d] + a4[r]);
        }
        uint2 pk = { cvtpk(xn[0], xn[1]), cvtpk(xn[2], xn[3]) };
        *(uint2*)&o0[((size_t)(b * NPIX + col)) * 256 + rbase] = pk;
      } else if (MODE == 1) {
        const int part = rbase >> 8, h = (rbase >> 5) & 7, dd = rbase & 31;
        if (part == 2) {           // V transposed: [b][h][d][n]
          #pragma unroll
          for (int r = 0; r < 4; ++r)
            o2[(((size_t)(b * 8 + h)) * 32 + dd + r) * NPIX + col] = f2b(a4[r]);
        } else {
          unsigned short* dst = part == 0 ? o0 : o1;
          const float sc = (part == 0) ? (QSCALE * L2E) : 1.0f;
          uint2 pk = { cvtpk(a4[0] * sc, a4[1] * sc), cvtpk(a4[2] * sc, a4[3] * sc) };
          *(uint2*)&dst[(((size_t)(b * 8 + h)) * NPIX + col) * 32 + dd] = pk;
        }
      } else {
        #pragma unroll
        for (int r = 0; r < 4; ++r) {
          int c = rbase + r;
          of[((size_t)(b * 256 + c)) * NPIX + col] = a4[r] + vec[c];
        }
      }
    }
  }
}

// ---------------------------------------------------------------------------
// Attention, round-quantization fix: grid = EXACTLY 256 blocks (16 bh x 16
// q-blocks of 144 queries), 9 waves/block (576 thr), 16 q/wave -- one
// dispatch round, zero CU tail (576-block grids ran 3 serial rounds of
// ~27us; 1152-block ran 5 x ~16us -- all measured walls ~81-95us).
// Inner loop = twice-validated lean R1/R4 body: LDS-staged bias tab (global
// u16 gather measured +14us when latency unhidden, R8), in-loop K/V frag
// loads, hoisted hj, f32 VALU lsum (ones-MFMA lsum forbidden: bf16 denom
// error 1.2e-3 > 1.55e-4 threshold, R7), exp2f, cvtpk P-pack.
// LDS: tab 18.1 KB + Pl 9x2.3 KB = 38.8 KB.
// ---------------------------------------------------------------------------
__global__ __launch_bounds__(576) void attn_k(
    const unsigned short* __restrict__ qg, const unsigned short* __restrict__ kg,
    const unsigned short* __restrict__ vt, const unsigned short* __restrict__ tabt,
    unsigned short* __restrict__ ob)
{
  __shared__ __align__(16) unsigned short tab[TBLP];     // 18.06 KB
  __shared__ __align__(16) unsigned short Pl[9][16][72]; // 20.7 KB, per-wave

  const int tid = threadIdx.x;
  const int w = tid >> 6, lane = tid & 63;
  const int lm = lane & 15, quad = lane >> 4;
  const int bh = blockIdx.x;
  const int q0 = blockIdx.y * 144;
  const size_t base = (size_t)bh * NPIX * 32;   // q/k base; also vt base

  { // stage per-head bias slice (already *L2E, bf16); TBLP = 8*1129
    const unsigned short* src = tabt + (size_t)(bh & 7) * TBLP;
    for (int e = tid * 8; e < TBLP; e += 4608)
      *(short8*)&tab[e] = *(const short8*)&src[e];
  }
  __syncthreads();   // only barrier in the kernel

  // Q fragment: B-operand for S^T (n=lm=q, k=quad*8+j=d); pre-scaled QSCALE*L2E
  const int q = q0 + w * 16 + lm;
  const short8 qfrag = *(const short8*)&qg[base + (size_t)q * 32 + quad * 8];

  // bias row base for this lane's query
  const int hi = (q * 43691) >> 21;                  // q / 48
  const int rb = (hi + 47) * 95 + (q - hi * 48) + 47;

  float lsum = 0.f;
  floatx4 o[2] = {};

  for (int t = 0; t < NTILES; ++t) {
    const int j0 = t * 64;
    // S^T[key][q]: rows = keys (quad*4+r per kt), cols = queries (lm)
    floatx4 s4[4];
    #pragma unroll
    for (int kt = 0; kt < 4; ++kt) {
      short8 kf = *(const short8*)&kg[base + (size_t)(j0 + kt * 16 + lm) * 32 + quad * 8];
      floatx4 z = {};
      s4[kt] = __builtin_amdgcn_mfma_f32_16x16x32_bf16(kf, qfrag, z, 0, 0, 0);
    }
    // + bias (LDS tab, idx descending in r; kk%4==0 so hj uniform over r),
    // exp2, accumulate l, pack P
    #pragma unroll
    for (int kt = 0; kt < 4; ++kt) {
      const int kk = j0 + kt * 16 + quad * 4;
      const int hj = (kk * 43691) >> 21;             // = key/48 for all 4 keys
      const int bb = rb - kk - hj * 47;              // tab idx for r=0
      float pv[4];
      #pragma unroll
      for (int r = 0; r < 4; ++r) {
        float p = exp2f(s4[kt][r] + b2f(tab[bb - r]));
        lsum += p;
        pv[r] = p;
      }
      uint2 pk = { cvtpk(pv[0], pv[1]), cvtpk(pv[2], pv[3]) };
      *(uint2*)&Pl[w][lm][kt * 16 + quad * 4] = pk;  // P[q][key] layout
    }
    __asm__ volatile("s_waitcnt lgkmcnt(0)" ::: "memory"); // wave-local DS order
    // O^T[d][q] += V^T[d][key] * P^T[key][q]
    #pragma unroll
    for (int c = 0; c < 2; ++c) {
      short8 pf = *(const short8*)&Pl[w][lm][c * 32 + quad * 8];
      #pragma unroll
      for (int dt = 0; dt < 2; ++dt) {
        short8 vf = *(const short8*)&vt[base + (size_t)(dt * 16 + lm) * NPIX + j0 + c * 32 + quad * 8];
        o[dt] = __builtin_amdgcn_mfma_f32_16x16x32_bf16(vf, pf, o[dt], 0, 0, 0);
      }
    }
  }

  // reduce l across the 4 quads holding the same query
  lsum += __shfl_xor(lsum, 16, 64);
  lsum += __shfl_xor(lsum, 32, 64);
  const float inv = 1.f / lsum;

  // store O[q][d] bf16: lane holds d = dt*16 + quad*4 + r at its query q
  #pragma unroll
  for (int dt = 0; dt < 2; ++dt) {
    uint2 pk = { cvtpk(o[dt][0] * inv, o[dt][1] * inv),
                 cvtpk(o[dt][2] * inv, o[dt][3] * inv) };
    *(uint2*)&ob[base + (size_t)q * 32 + dt * 16 + quad * 4] = pk;
  }
}

// ---------------------------------------------------------------------------
extern "C" void kernel_launch(void* const* d_in, const int* in_sizes, int n_in,
                              void* d_out, int out_size, void* d_ws, size_t ws_size,
                              hipStream_t stream) {
  const float* x     = (const float*)d_in[0];
  const float* beta  = (const float*)d_in[1];
  const float* gamma = (const float*)d_in[2];
  const float* wqkv  = (const float*)d_in[3];
  const float* wout  = (const float*)d_in[4];
  const float* bout  = (const float*)d_in[5];
  const float* table = (const float*)d_in[6];
  float* out = (float*)d_out;   // reference output dtype is float32

  unsigned short* ws = (unsigned short*)d_ws;
  const size_t NE = (size_t)NB * NPIX * 256;   // 1,179,648 elems per tensor
  unsigned short* xn_t  = ws;                  // [b][n][256] bf16
  unsigned short* qbuf  = ws + NE;             // [b][h][n][32] bf16, *QSCALE*L2E
  unsigned short* kbuf  = ws + 2 * NE;         // [b][h][n][32]
  unsigned short* vtbuf = ws + 3 * NE;         // [b][h][32][n]  (transposed)
  unsigned short* obuf  = ws + 4 * NE;         // [b][h][n][32] == res[b][n2][e]
  // bf16 weights: gamma/wqkv alias obuf (dead before attn writes it)
  unsigned short* gam_b = obuf;                // 65536
  unsigned short* qkv_b = obuf + 65536;        // 196608 (fits in NE)
  unsigned short* out_b = ws + 5 * NE;         // 65536 (live through gemm2)
  unsigned short* tab_t = ws + 5 * NE + 65536; // 8*TBLP (live through attn)
  // xsq aliases qbuf: written by prep, consumed by gemm0, overwritten by gemm1
  unsigned short* xsq   = qbuf;                // [b][n][256] bf16 = x^2 transposed

  prep_k<<<1056, 256, 0, stream>>>(gamma, wqkv, wout, table, x,
                                   gam_b, qkv_b, out_b, tab_t, xsq);
  gemm_k<0><<<dim3(36, 4, 2), 256, 0, stream>>>(gam_b, xsq, beta, x,
                                                xn_t, nullptr, nullptr, nullptr);
  gemm_k<1><<<dim3(36, 12, 2), 256, 0, stream>>>(qkv_b, xn_t, nullptr, nullptr,
                                                 qbuf, kbuf, vtbuf, nullptr);
  attn_k<<<dim3(16, 16), 576, 0, stream>>>(qbuf, kbuf, vtbuf, tab_t, obuf);
  gemm_k<2><<<dim3(36, 4, 2), 256, 0, stream>>>(out_b, obuf, bout, nullptr,
                                                nullptr, nullptr, nullptr, out);
}